// Round 1
// baseline (372.969 us; speedup 1.0000x reference)
//
#include <hip/hip_runtime.h>

#define COULOMB_CONST 7.1998226f

// One block handles ROWS_PER_BLOCK consecutive rows of one batch's d_ij.
// Each element contributes q_j * rcp(d_ij); row sum is scaled by q_i.
__global__ __launch_bounds__(256) void coulomb_kernel(
    const float* __restrict__ d_ij,
    const float* __restrict__ q,
    float* __restrict__ out,
    int N, int rowsPerBlock, int blocksPerBatch)
{
    extern __shared__ float q_lds[];   // N floats: q[b][0..N-1]

    const int b   = blockIdx.x / blocksPerBatch;
    const int blk = blockIdx.x % blocksPerBatch;
    const int t   = threadIdx.x;

    // Stage q[b][:] into LDS (vectorized, coalesced).
    const float4* q4 = (const float4*)(q + (size_t)b * N);
    for (int i = t; i < N / 4; i += (int)blockDim.x)
        ((float4*)q_lds)[i] = q4[i];
    __syncthreads();

    const int vecPerRow = N / 4;             // 512 for N=2048
    const int row0 = blk * rowsPerBlock;

    float acc = 0.0f;
    for (int r = 0; r < rowsPerBlock; ++r) {
        const int row = row0 + r;
        const float4* dp =
            (const float4*)(d_ij + ((size_t)b * N + (size_t)row) * N);
        float s = 0.0f;
        for (int v = t; v < vecPerRow; v += (int)blockDim.x) {
            const float4 d4 = dp[v];                       // coalesced 16B/lane
            const float4 qv = ((const float4*)q_lds)[v];
            s = fmaf(qv.x, __builtin_amdgcn_rcpf(d4.x), s);
            s = fmaf(qv.y, __builtin_amdgcn_rcpf(d4.y), s);
            s = fmaf(qv.z, __builtin_amdgcn_rcpf(d4.z), s);
            s = fmaf(qv.w, __builtin_amdgcn_rcpf(d4.w), s);
        }
        acc = fmaf(q_lds[row], s, acc);      // q_i * sum_j q_j/d_ij
    }

    // Wave64 shuffle reduction.
    for (int off = 32; off > 0; off >>= 1)
        acc += __shfl_down(acc, off, 64);

    __shared__ float wsum[4];
    const int lane = t & 63, wid = t >> 6;
    if (lane == 0) wsum[wid] = acc;
    __syncthreads();
    if (t == 0) {
        const float tot = (wsum[0] + wsum[1]) + (wsum[2] + wsum[3]);
        atomicAdd(&out[b], COULOMB_CONST * tot);
    }
}

extern "C" void kernel_launch(void* const* d_in, const int* in_sizes, int n_in,
                              void* d_out, int out_size, void* d_ws, size_t ws_size,
                              hipStream_t stream) {
    const float* d_dij = (const float*)d_in[0];
    const float* d_q   = (const float*)d_in[1];
    float* out = (float*)d_out;

    // B*N = in_sizes[1], B*N*N = in_sizes[0]  ->  N = sizes0/sizes1
    const long long sz_d = in_sizes[0];
    const long long sz_q = in_sizes[1];
    const int N = (int)(sz_d / sz_q);
    const int B = (int)(sz_q / N);

    const int rowsPerBlock   = 8;
    const int blocksPerBatch = N / rowsPerBlock;   // 256 for N=2048
    const int grid = B * blocksPerBatch;           // 4096

    // d_out is poisoned (0xAA) before every timed launch — zero it.
    hipMemsetAsync(d_out, 0, (size_t)out_size * sizeof(float), stream);

    const size_t ldsBytes = (size_t)N * sizeof(float);
    coulomb_kernel<<<grid, 256, ldsBytes, stream>>>(
        d_dij, d_q, out, N, rowsPerBlock, blocksPerBatch);
}

// Round 2
// 355.590 us; speedup vs baseline: 1.0489x; 1.0489x over previous
//
#include <hip/hip_runtime.h>

#define COULOMB_CONST 7.1998226f

constexpr int TPB = 256;

// ---------- specialized path: N known at compile time, fully unrolled ----------
// One block = ROWS consecutive rows of one batch. All ROWS*VPR float4 loads are
// issued before consumption (256 B/thread in flight) to hide HBM latency.
template<int N, int ROWS>
__global__ __launch_bounds__(TPB) void coulomb_spec(
    const float* __restrict__ d_ij,
    const float* __restrict__ q,
    float* __restrict__ partial,
    int blocksPerBatch)
{
    constexpr int VPR = N / 4 / TPB;          // float4 loads per thread per row
    __shared__ float q_lds[N];

    const int b   = blockIdx.x / blocksPerBatch;
    const int blk = blockIdx.x % blocksPerBatch;
    const int t   = threadIdx.x;

    const float4* q4 = (const float4*)(q + (size_t)b * N);
    #pragma unroll
    for (int i = 0; i < VPR; ++i)
        ((float4*)q_lds)[t + i * TPB] = q4[t + i * TPB];
    __syncthreads();

    const int row0 = blk * ROWS;
    const float* base = d_ij + ((size_t)b * N + (size_t)row0) * N;

    // Issue ALL loads first — maximize memory-level parallelism.
    float4 d4[ROWS][VPR];
    #pragma unroll
    for (int r = 0; r < ROWS; ++r) {
        const float4* dp = (const float4*)(base + (size_t)r * N);
        #pragma unroll
        for (int v = 0; v < VPR; ++v)
            d4[r][v] = dp[t + v * TPB];
    }

    float acc = 0.0f;
    #pragma unroll
    for (int r = 0; r < ROWS; ++r) {
        float s = 0.0f;
        #pragma unroll
        for (int v = 0; v < VPR; ++v) {
            const float4 qv = ((const float4*)q_lds)[t + v * TPB];
            const float4 dv = d4[r][v];
            s = fmaf(qv.x, __builtin_amdgcn_rcpf(dv.x), s);
            s = fmaf(qv.y, __builtin_amdgcn_rcpf(dv.y), s);
            s = fmaf(qv.z, __builtin_amdgcn_rcpf(dv.z), s);
            s = fmaf(qv.w, __builtin_amdgcn_rcpf(dv.w), s);
        }
        acc = fmaf(q_lds[row0 + r], s, acc);   // q_i * sum_j q_j/d_ij
    }

    for (int off = 32; off > 0; off >>= 1)
        acc += __shfl_down(acc, off, 64);

    __shared__ float wsum[TPB / 64];
    const int lane = t & 63, wid = t >> 6;
    if (lane == 0) wsum[wid] = acc;
    __syncthreads();
    if (t == 0)
        partial[blockIdx.x] = (wsum[0] + wsum[1]) + (wsum[2] + wsum[3]);
}

// out[b] = COULOMB * sum_i partial[b*blocksPerBatch + i]  (writes every element
// of d_out — no pre-zeroing needed, deterministic, no atomics)
__global__ __launch_bounds__(TPB) void coulomb_reduce(
    const float* __restrict__ partial, float* __restrict__ out,
    int blocksPerBatch)
{
    const int b = blockIdx.x;
    const int t = threadIdx.x;
    float s = 0.0f;
    for (int i = t; i < blocksPerBatch; i += TPB)
        s += partial[(size_t)b * blocksPerBatch + i];
    for (int off = 32; off > 0; off >>= 1)
        s += __shfl_down(s, off, 64);
    __shared__ float wsum[TPB / 64];
    const int lane = t & 63, wid = t >> 6;
    if (lane == 0) wsum[wid] = s;
    __syncthreads();
    if (t == 0)
        out[b] = COULOMB_CONST * ((wsum[0] + wsum[1]) + (wsum[2] + wsum[3]));
}

// ---------- generic fallback (any N divisible by 4) ----------
__global__ __launch_bounds__(TPB) void coulomb_generic(
    const float* __restrict__ d_ij,
    const float* __restrict__ q,
    float* __restrict__ out,
    int N, int rowsPerBlock, int blocksPerBatch)
{
    extern __shared__ float q_dyn[];
    const int b   = blockIdx.x / blocksPerBatch;
    const int blk = blockIdx.x % blocksPerBatch;
    const int t   = threadIdx.x;

    const float4* q4 = (const float4*)(q + (size_t)b * N);
    for (int i = t; i < N / 4; i += TPB)
        ((float4*)q_dyn)[i] = q4[i];
    __syncthreads();

    const int vecPerRow = N / 4;
    const int row0 = blk * rowsPerBlock;
    float acc = 0.0f;
    for (int r = 0; r < rowsPerBlock; ++r) {
        const int row = row0 + r;
        const float4* dp = (const float4*)(d_ij + ((size_t)b * N + (size_t)row) * N);
        float s = 0.0f;
        for (int v = t; v < vecPerRow; v += TPB) {
            const float4 d4 = dp[v];
            const float4 qv = ((const float4*)q_dyn)[v];
            s = fmaf(qv.x, __builtin_amdgcn_rcpf(d4.x), s);
            s = fmaf(qv.y, __builtin_amdgcn_rcpf(d4.y), s);
            s = fmaf(qv.z, __builtin_amdgcn_rcpf(d4.z), s);
            s = fmaf(qv.w, __builtin_amdgcn_rcpf(d4.w), s);
        }
        acc = fmaf(q_dyn[row], s, acc);
    }
    for (int off = 32; off > 0; off >>= 1)
        acc += __shfl_down(acc, off, 64);
    __shared__ float wsum[TPB / 64];
    const int lane = t & 63, wid = t >> 6;
    if (lane == 0) wsum[wid] = acc;
    __syncthreads();
    if (t == 0) {
        const float tot = (wsum[0] + wsum[1]) + (wsum[2] + wsum[3]);
        atomicAdd(&out[b], COULOMB_CONST * tot);
    }
}

extern "C" void kernel_launch(void* const* d_in, const int* in_sizes, int n_in,
                              void* d_out, int out_size, void* d_ws, size_t ws_size,
                              hipStream_t stream) {
    const float* d_dij = (const float*)d_in[0];
    const float* d_q   = (const float*)d_in[1];
    float* out = (float*)d_out;

    const long long sz_d = in_sizes[0];
    const long long sz_q = in_sizes[1];
    const int N = (int)(sz_d / sz_q);
    const int B = (int)(sz_q / N);

    if (N == 2048) {
        constexpr int ROWS = 8;
        const int blocksPerBatch = 2048 / ROWS;      // 256
        const int grid = B * blocksPerBatch;         // 4096
        float* partial = (float*)d_ws;               // 16 KB scratch
        coulomb_spec<2048, ROWS><<<grid, TPB, 0, stream>>>(
            d_dij, d_q, partial, blocksPerBatch);
        coulomb_reduce<<<B, TPB, 0, stream>>>(partial, out, blocksPerBatch);
    } else {
        const int rowsPerBlock = 8;
        const int blocksPerBatch = (N + rowsPerBlock - 1) / rowsPerBlock;
        const int grid = B * blocksPerBatch;
        hipMemsetAsync(d_out, 0, (size_t)out_size * sizeof(float), stream);
        const size_t ldsBytes = (size_t)N * sizeof(float);
        coulomb_generic<<<grid, TPB, ldsBytes, stream>>>(
            d_dij, d_q, out, N, rowsPerBlock, blocksPerBatch);
    }
}

// Round 3
// 355.244 us; speedup vs baseline: 1.0499x; 1.0010x over previous
//
#include <hip/hip_runtime.h>

#define COULOMB_CONST 7.1998226f

constexpr int TPB = 256;

// ---------- specialized path: N known at compile time, fully unrolled ----------
// One block = ROWS consecutive rows of one batch.
// sum_ij q_i q_j / d_ij = sum_i q_i * (sum_j q_j / d_ij).
// Column-q (qv) is row-invariant -> held in registers, loaded once.
// Row-q (q[row0+r]) is block-uniform -> scalar loads, no LDS needed.
template<int N, int ROWS>
__global__ __launch_bounds__(TPB) void coulomb_spec(
    const float* __restrict__ d_ij,
    const float* __restrict__ q,
    float* __restrict__ partial,
    int blocksPerBatch)
{
    constexpr int VPR = N / 4 / TPB;          // float4 loads per thread per row (2)

    const int b   = blockIdx.x / blocksPerBatch;
    const int blk = blockIdx.x % blocksPerBatch;
    const int t   = threadIdx.x;

    const int row0 = blk * ROWS;
    const float* qb   = q + (size_t)b * N;
    const float* base = d_ij + ((size_t)b * N + (size_t)row0) * N;

    // Column q values for this thread's lanes — reused across all ROWS rows.
    float4 qv[VPR];
    #pragma unroll
    for (int v = 0; v < VPR; ++v)
        qv[v] = ((const float4*)qb)[t + v * TPB];

    // Issue ALL d_ij loads before consumption — 256 B/thread in flight.
    float4 d4[ROWS][VPR];
    #pragma unroll
    for (int r = 0; r < ROWS; ++r) {
        const float4* dp = (const float4*)(base + (size_t)r * N);
        #pragma unroll
        for (int v = 0; v < VPR; ++v)
            d4[r][v] = dp[t + v * TPB];
    }

    float acc = 0.0f;
    #pragma unroll
    for (int r = 0; r < ROWS; ++r) {
        float s = 0.0f;
        #pragma unroll
        for (int v = 0; v < VPR; ++v) {
            const float4 dv = d4[r][v];
            s = fmaf(qv[v].x, __builtin_amdgcn_rcpf(dv.x), s);
            s = fmaf(qv[v].y, __builtin_amdgcn_rcpf(dv.y), s);
            s = fmaf(qv[v].z, __builtin_amdgcn_rcpf(dv.z), s);
            s = fmaf(qv[v].w, __builtin_amdgcn_rcpf(dv.w), s);
        }
        acc = fmaf(qb[row0 + r], s, acc);     // block-uniform scalar load
    }

    // Wave64 shuffle reduction, then cross-wave via 4 floats of LDS.
    for (int off = 32; off > 0; off >>= 1)
        acc += __shfl_down(acc, off, 64);

    __shared__ float wsum[TPB / 64];
    const int lane = t & 63, wid = t >> 6;
    if (lane == 0) wsum[wid] = acc;
    __syncthreads();
    if (t == 0)
        partial[blockIdx.x] = (wsum[0] + wsum[1]) + (wsum[2] + wsum[3]);
}

// out[b] = COULOMB * sum_i partial[b*blocksPerBatch + i]  (writes every element
// of d_out — no pre-zeroing needed, deterministic, no atomics)
__global__ __launch_bounds__(TPB) void coulomb_reduce(
    const float* __restrict__ partial, float* __restrict__ out,
    int blocksPerBatch)
{
    const int b = blockIdx.x;
    const int t = threadIdx.x;
    float s = 0.0f;
    for (int i = t; i < blocksPerBatch; i += TPB)
        s += partial[(size_t)b * blocksPerBatch + i];
    for (int off = 32; off > 0; off >>= 1)
        s += __shfl_down(s, off, 64);
    __shared__ float wsum[TPB / 64];
    const int lane = t & 63, wid = t >> 6;
    if (lane == 0) wsum[wid] = s;
    __syncthreads();
    if (t == 0)
        out[b] = COULOMB_CONST * ((wsum[0] + wsum[1]) + (wsum[2] + wsum[3]));
}

// ---------- generic fallback (any N divisible by 4) ----------
__global__ __launch_bounds__(TPB) void coulomb_generic(
    const float* __restrict__ d_ij,
    const float* __restrict__ q,
    float* __restrict__ out,
    int N, int rowsPerBlock, int blocksPerBatch)
{
    extern __shared__ float q_dyn[];
    const int b   = blockIdx.x / blocksPerBatch;
    const int blk = blockIdx.x % blocksPerBatch;
    const int t   = threadIdx.x;

    const float4* q4 = (const float4*)(q + (size_t)b * N);
    for (int i = t; i < N / 4; i += TPB)
        ((float4*)q_dyn)[i] = q4[i];
    __syncthreads();

    const int vecPerRow = N / 4;
    const int row0 = blk * rowsPerBlock;
    float acc = 0.0f;
    for (int r = 0; r < rowsPerBlock; ++r) {
        const int row = row0 + r;
        const float4* dp = (const float4*)(d_ij + ((size_t)b * N + (size_t)row) * N);
        float s = 0.0f;
        for (int v = t; v < vecPerRow; v += TPB) {
            const float4 d4 = dp[v];
            const float4 qv = ((const float4*)q_dyn)[v];
            s = fmaf(qv.x, __builtin_amdgcn_rcpf(d4.x), s);
            s = fmaf(qv.y, __builtin_amdgcn_rcpf(d4.y), s);
            s = fmaf(qv.z, __builtin_amdgcn_rcpf(d4.z), s);
            s = fmaf(qv.w, __builtin_amdgcn_rcpf(d4.w), s);
        }
        acc = fmaf(q_dyn[row], s, acc);
    }
    for (int off = 32; off > 0; off >>= 1)
        acc += __shfl_down(acc, off, 64);
    __shared__ float wsum[TPB / 64];
    const int lane = t & 63, wid = t >> 6;
    if (lane == 0) wsum[wid] = acc;
    __syncthreads();
    if (t == 0) {
        const float tot = (wsum[0] + wsum[1]) + (wsum[2] + wsum[3]);
        atomicAdd(&out[b], COULOMB_CONST * tot);
    }
}

extern "C" void kernel_launch(void* const* d_in, const int* in_sizes, int n_in,
                              void* d_out, int out_size, void* d_ws, size_t ws_size,
                              hipStream_t stream) {
    const float* d_dij = (const float*)d_in[0];
    const float* d_q   = (const float*)d_in[1];
    float* out = (float*)d_out;

    const long long sz_d = in_sizes[0];
    const long long sz_q = in_sizes[1];
    const int N = (int)(sz_d / sz_q);
    const int B = (int)(sz_q / N);

    if (N == 2048) {
        constexpr int ROWS = 8;
        const int blocksPerBatch = 2048 / ROWS;      // 256
        const int grid = B * blocksPerBatch;         // 4096
        float* partial = (float*)d_ws;               // 16 KB scratch
        coulomb_spec<2048, ROWS><<<grid, TPB, 0, stream>>>(
            d_dij, d_q, partial, blocksPerBatch);
        coulomb_reduce<<<B, TPB, 0, stream>>>(partial, out, blocksPerBatch);
    } else {
        const int rowsPerBlock = 8;
        const int blocksPerBatch = (N + rowsPerBlock - 1) / rowsPerBlock;
        const int grid = B * blocksPerBatch;
        hipMemsetAsync(d_out, 0, (size_t)out_size * sizeof(float), stream);
        const size_t ldsBytes = (size_t)N * sizeof(float);
        coulomb_generic<<<grid, TPB, ldsBytes, stream>>>(
            d_dij, d_q, out, N, rowsPerBlock, blocksPerBatch);
    }
}

// Round 4
// 354.323 us; speedup vs baseline: 1.0526x; 1.0026x over previous
//
#include <hip/hip_runtime.h>

#define COULOMB_CONST 7.1998226f

constexpr int TPB = 256;

// ---------- specialized path: N known at compile time, fully unrolled ----------
// One block = ROWS consecutive rows of one batch.
// sum_ij q_i q_j / d_ij = sum_i q_i * (sum_j q_j / d_ij).
// Column-q (qv) is row-invariant -> held in registers, loaded once.
// Row-q (q[row0+r]) is block-uniform -> scalar loads, no LDS needed.
// ROWS=4: d4 = 8 float4 = 32 data VGPRs -> ~65 total, high occupancy.
template<int N, int ROWS>
__global__ __launch_bounds__(TPB) void coulomb_spec(
    const float* __restrict__ d_ij,
    const float* __restrict__ q,
    float* __restrict__ partial,
    int blocksPerBatch)
{
    constexpr int VPR = N / 4 / TPB;          // float4 loads per thread per row (2)

    const int b   = blockIdx.x / blocksPerBatch;
    const int blk = blockIdx.x % blocksPerBatch;
    const int t   = threadIdx.x;

    const int row0 = blk * ROWS;
    const float* qb   = q + (size_t)b * N;
    const float* base = d_ij + ((size_t)b * N + (size_t)row0) * N;

    // Column q values for this thread's lanes — reused across all ROWS rows.
    float4 qv[VPR];
    #pragma unroll
    for (int v = 0; v < VPR; ++v)
        qv[v] = ((const float4*)qb)[t + v * TPB];

    // Issue ALL d_ij loads before consumption — 128 B/thread in flight.
    float4 d4[ROWS][VPR];
    #pragma unroll
    for (int r = 0; r < ROWS; ++r) {
        const float4* dp = (const float4*)(base + (size_t)r * N);
        #pragma unroll
        for (int v = 0; v < VPR; ++v)
            d4[r][v] = dp[t + v * TPB];
    }

    float acc = 0.0f;
    #pragma unroll
    for (int r = 0; r < ROWS; ++r) {
        float s = 0.0f;
        #pragma unroll
        for (int v = 0; v < VPR; ++v) {
            const float4 dv = d4[r][v];
            s = fmaf(qv[v].x, __builtin_amdgcn_rcpf(dv.x), s);
            s = fmaf(qv[v].y, __builtin_amdgcn_rcpf(dv.y), s);
            s = fmaf(qv[v].z, __builtin_amdgcn_rcpf(dv.z), s);
            s = fmaf(qv[v].w, __builtin_amdgcn_rcpf(dv.w), s);
        }
        acc = fmaf(qb[row0 + r], s, acc);     // block-uniform scalar load
    }

    // Wave64 shuffle reduction, then cross-wave via 4 floats of LDS.
    for (int off = 32; off > 0; off >>= 1)
        acc += __shfl_down(acc, off, 64);

    __shared__ float wsum[TPB / 64];
    const int lane = t & 63, wid = t >> 6;
    if (lane == 0) wsum[wid] = acc;
    __syncthreads();
    if (t == 0)
        partial[blockIdx.x] = (wsum[0] + wsum[1]) + (wsum[2] + wsum[3]);
}

// out[b] = COULOMB * sum_i partial[b*blocksPerBatch + i]  (writes every element
// of d_out — no pre-zeroing needed, deterministic, no atomics)
__global__ __launch_bounds__(TPB) void coulomb_reduce(
    const float* __restrict__ partial, float* __restrict__ out,
    int blocksPerBatch)
{
    const int b = blockIdx.x;
    const int t = threadIdx.x;
    float s = 0.0f;
    for (int i = t; i < blocksPerBatch; i += TPB)
        s += partial[(size_t)b * blocksPerBatch + i];
    for (int off = 32; off > 0; off >>= 1)
        s += __shfl_down(s, off, 64);
    __shared__ float wsum[TPB / 64];
    const int lane = t & 63, wid = t >> 6;
    if (lane == 0) wsum[wid] = s;
    __syncthreads();
    if (t == 0)
        out[b] = COULOMB_CONST * ((wsum[0] + wsum[1]) + (wsum[2] + wsum[3]));
}

// ---------- generic fallback (any N divisible by 4) ----------
__global__ __launch_bounds__(TPB) void coulomb_generic(
    const float* __restrict__ d_ij,
    const float* __restrict__ q,
    float* __restrict__ out,
    int N, int rowsPerBlock, int blocksPerBatch)
{
    extern __shared__ float q_dyn[];
    const int b   = blockIdx.x / blocksPerBatch;
    const int blk = blockIdx.x % blocksPerBatch;
    const int t   = threadIdx.x;

    const float4* q4 = (const float4*)(q + (size_t)b * N);
    for (int i = t; i < N / 4; i += TPB)
        ((float4*)q_dyn)[i] = q4[i];
    __syncthreads();

    const int vecPerRow = N / 4;
    const int row0 = blk * rowsPerBlock;
    float acc = 0.0f;
    for (int r = 0; r < rowsPerBlock; ++r) {
        const int row = row0 + r;
        const float4* dp = (const float4*)(d_ij + ((size_t)b * N + (size_t)row) * N);
        float s = 0.0f;
        for (int v = t; v < vecPerRow; v += TPB) {
            const float4 d4 = dp[v];
            const float4 qv = ((const float4*)q_dyn)[v];
            s = fmaf(qv.x, __builtin_amdgcn_rcpf(d4.x), s);
            s = fmaf(qv.y, __builtin_amdgcn_rcpf(d4.y), s);
            s = fmaf(qv.z, __builtin_amdgcn_rcpf(d4.z), s);
            s = fmaf(qv.w, __builtin_amdgcn_rcpf(d4.w), s);
        }
        acc = fmaf(q_dyn[row], s, acc);
    }
    for (int off = 32; off > 0; off >>= 1)
        acc += __shfl_down(acc, off, 64);
    __shared__ float wsum[TPB / 64];
    const int lane = t & 63, wid = t >> 6;
    if (lane == 0) wsum[wid] = acc;
    __syncthreads();
    if (t == 0) {
        const float tot = (wsum[0] + wsum[1]) + (wsum[2] + wsum[3]);
        atomicAdd(&out[b], COULOMB_CONST * tot);
    }
}

extern "C" void kernel_launch(void* const* d_in, const int* in_sizes, int n_in,
                              void* d_out, int out_size, void* d_ws, size_t ws_size,
                              hipStream_t stream) {
    const float* d_dij = (const float*)d_in[0];
    const float* d_q   = (const float*)d_in[1];
    float* out = (float*)d_out;

    const long long sz_d = in_sizes[0];
    const long long sz_q = in_sizes[1];
    const int N = (int)(sz_d / sz_q);
    const int B = (int)(sz_q / N);

    if (N == 2048) {
        constexpr int ROWS = 4;
        const int blocksPerBatch = 2048 / ROWS;      // 512
        const int grid = B * blocksPerBatch;         // 8192
        float* partial = (float*)d_ws;               // 32 KB scratch
        coulomb_spec<2048, ROWS><<<grid, TPB, 0, stream>>>(
            d_dij, d_q, partial, blocksPerBatch);
        coulomb_reduce<<<B, TPB, 0, stream>>>(partial, out, blocksPerBatch);
    } else {
        const int rowsPerBlock = 8;
        const int blocksPerBatch = (N + rowsPerBlock - 1) / rowsPerBlock;
        const int grid = B * blocksPerBatch;
        hipMemsetAsync(d_out, 0, (size_t)out_size * sizeof(float), stream);
        const size_t ldsBytes = (size_t)N * sizeof(float);
        coulomb_generic<<<grid, TPB, ldsBytes, stream>>>(
            d_dij, d_q, out, N, rowsPerBlock, blocksPerBatch);
    }
}